// Round 1
// baseline (959.647 us; speedup 1.0000x reference)
//
#include <hip/hip_runtime.h>
#include <math.h>

#define NB     32768
#define DIN    784
#define DH     256
#define DOUT   10
#define NSEG   20
#define SEGLEN 50
#define EPSBN  1e-5f
#define SCRT   0.031622776601683794f   // sqrt(0.001)

__device__ __forceinline__ float2 cmul(float2 a, float2 b) {
    return make_float2(fmaf(a.x, b.x, -(a.y*b.y)), fmaf(a.x, b.y, a.y*b.x));
}
__device__ __forceinline__ float2 cadd(float2 a, float2 b){ return make_float2(a.x+b.x, a.y+b.y); }
__device__ __forceinline__ float2 csub(float2 a, float2 b){ return make_float2(a.x-b.x, a.y-b.y); }

__device__ __forceinline__ int physi(int i){ return i ^ ((i >> 4) & 15); }  // bijective LDS swizzle

__device__ __forceinline__ float wave_sum(float v) {
    #pragma unroll
    for (int m = 32; m > 0; m >>= 1) v += __shfl_xor(v, m, 64);
    return v;
}

// ---------------- prep: H^50 (fp64) + zero BN stat accumulators ----------------
__global__ void prep_kernel(const float* __restrict__ Hr, const float* __restrict__ Hi,
                            float2* __restrict__ Heff, float* __restrict__ stats /*1024 floats*/)
{
    int j = threadIdx.x;            // 0..255
    stats[j] = 0.f; stats[256+j] = 0.f; stats[512+j] = 0.f; stats[768+j] = 0.f;
    for (int s = 0; s < NSEG; ++s) {
        double ar = (double)Hr[s*DH + j], ai = (double)Hi[s*DH + j];
        double pr = 1.0, pi = 0.0;
        for (int k = 0; k < SEGLEN; ++k) {
            double nr = pr*ar - pi*ai;
            pi = pr*ai + pi*ar;
            pr = nr;
        }
        Heff[s*DH + j] = make_float2((float)pr, (float)pi);
    }
}

// ---------------- GEMM1: t = x @ W1 + b1 (fp32, 64x64 tile, 4x4/thread) ----------------
__global__ __launch_bounds__(256) void gemm1_kernel(const float* __restrict__ x,
                                                    const float* __restrict__ W1,
                                                    const float* __restrict__ b1,
                                                    float* __restrict__ t)
{
    __shared__ __attribute__((aligned(16))) float As[16][68];   // [k][row], padded
    __shared__ __attribute__((aligned(16))) float Bs[16][64];   // [k][col]
    const int bm = blockIdx.x * 64;
    const int bn = blockIdx.y * 64;
    const int tid = threadIdx.x;
    const int tx = tid & 15, ty = tid >> 4;
    const int arow = tid >> 2, acol = (tid & 3) << 2;
    const int brow = tid >> 4, bcol = (tid & 15) << 2;
    const float* xp = x + (size_t)(bm + arow) * DIN + acol;
    const float* wp = W1 + (size_t)brow * DH + bn + bcol;
    float acc[4][4] = {};
    for (int k0 = 0; k0 < DIN; k0 += 16) {
        float4 av = *(const float4*)(xp + k0);
        float4 bv = *(const float4*)(wp + (size_t)k0 * DH);
        __syncthreads();
        As[acol+0][arow] = av.x; As[acol+1][arow] = av.y;
        As[acol+2][arow] = av.z; As[acol+3][arow] = av.w;
        *(float4*)&Bs[brow][bcol] = bv;
        __syncthreads();
        #pragma unroll
        for (int kk = 0; kk < 16; ++kk) {
            float4 a4 = *(const float4*)&As[kk][ty<<2];
            float4 b4 = *(const float4*)&Bs[kk][tx<<2];
            float ar[4] = {a4.x,a4.y,a4.z,a4.w};
            float br[4] = {b4.x,b4.y,b4.z,b4.w};
            #pragma unroll
            for (int i2 = 0; i2 < 4; ++i2)
                #pragma unroll
                for (int j2 = 0; j2 < 4; ++j2)
                    acc[i2][j2] = fmaf(ar[i2], br[j2], acc[i2][j2]);
        }
    }
    const float4 bb = *(const float4*)&b1[bn + (tx<<2)];
    #pragma unroll
    for (int i2 = 0; i2 < 4; ++i2) {
        int row = bm + (ty<<2) + i2;
        float4 o;
        o.x = acc[i2][0] + bb.x; o.y = acc[i2][1] + bb.y;
        o.z = acc[i2][2] + bb.z; o.w = acc[i2][3] + bb.w;
        *(float4*)&t[(size_t)row * DH + bn + (tx<<2)] = o;
    }
}

// ---------------- column stats (sum, sumsq) via block partials + atomics ----------------
__global__ __launch_bounds__(256) void colstats_kernel(const float* __restrict__ t,
                                                       float* __restrict__ sum,
                                                       float* __restrict__ ssq)
{
    const int col = threadIdx.x;
    float s = 0.f, q = 0.f;
    for (int r = blockIdx.x; r < NB; r += gridDim.x) {
        float v = t[(size_t)r * DH + col];
        s += v; q = fmaf(v, v, q);
    }
    atomicAdd(&sum[col], s);
    atomicAdd(&ssq[col], q);
}

__global__ void finalize_kernel(float* __restrict__ st /* [0..255]=sum -> mu, [256..511]=ssq -> rstd */)
{
    int j = threadIdx.x;
    float mu = st[j] * (1.f/(float)NB);
    float var = st[DH+j] * (1.f/(float)NB) - mu*mu;
    st[j] = mu;
    st[DH+j] = rsqrtf(var + EPSBN);
}

// ---------------- FFT pieces (radix-4 Stockham, N=256, 1 wave per row) ----------------
// layout: reg r <-> point (lane + 64*r). Stages 0 and 3 are register-local; 1,2 via LDS.
template<bool FWD>
__device__ __forceinline__ void fft_stage0(const float2 X[4], float2* dst, int lane, float wc, float ws)
{
    float2 a=X[0], b=X[1], c=X[2], d=X[3];
    float2 t0 = cadd(a,c), t1 = csub(a,c), t2 = cadd(b,d), bd = csub(b,d);
    float2 t3 = FWD ? make_float2(bd.y, -bd.x) : make_float2(-bd.y, bd.x);
    float2 w1 = make_float2(wc, FWD ? -ws : ws);
    float2 w2 = cmul(w1,w1);
    float2 w3 = cmul(w2,w1);
    int j = lane << 2;
    dst[physi(j)]   = cadd(t0,t2);
    dst[physi(j+1)] = cmul(cadd(t1,t3), w1);
    dst[physi(j+2)] = cmul(csub(t0,t2), w2);
    dst[physi(j+3)] = cmul(csub(t1,t3), w3);
}

template<int TT, bool FWD>
__device__ __forceinline__ void fft_stage_lds(const float2* src, float2* dst, int lane, float wc, float ws)
{
    const int s_ = 1 << (2*TT);
    int i = lane;
    float2 a = src[physi(i)];
    float2 b = src[physi(i+64)];
    float2 c = src[physi(i+128)];
    float2 d = src[physi(i+192)];
    float2 t0 = cadd(a,c), t1 = csub(a,c), t2 = cadd(b,d), bd = csub(b,d);
    float2 t3 = FWD ? make_float2(bd.y, -bd.x) : make_float2(-bd.y, bd.x);
    float2 w1 = make_float2(wc, FWD ? -ws : ws);
    float2 w2 = cmul(w1,w1);
    float2 w3 = cmul(w2,w1);
    int j = i + 3*(i & ~(s_-1));
    dst[physi(j)]      = cadd(t0,t2);
    dst[physi(j+s_)]   = cmul(cadd(t1,t3), w1);
    dst[physi(j+2*s_)] = cmul(csub(t0,t2), w2);
    dst[physi(j+3*s_)] = cmul(csub(t1,t3), w3);
}

template<bool FWD>
__device__ __forceinline__ void fft_stage3(const float2* src, float2 X[4], int lane)
{
    float2 a = src[physi(lane)];
    float2 b = src[physi(lane+64)];
    float2 c = src[physi(lane+128)];
    float2 d = src[physi(lane+192)];
    float2 t0 = cadd(a,c), t1 = csub(a,c), t2 = cadd(b,d), bd = csub(b,d);
    float2 t3 = FWD ? make_float2(bd.y, -bd.x) : make_float2(-bd.y, bd.x);
    X[0] = cadd(t0,t2);
    X[1] = cadd(t1,t3);
    X[2] = csub(t0,t2);
    X[3] = csub(t1,t3);
}

// ---------------- segments kernel: BN1+relu then 20x (log0 -> fft -> filt -> ifft -> exp0 -> res) ----------------
__global__ __launch_bounds__(256) void seg_kernel(
    float* __restrict__ t, const float2* __restrict__ Heff,
    const float* __restrict__ st1,
    const float* __restrict__ g1, const float* __restrict__ be1,
    const float* __restrict__ alphas, const float* __restrict__ betas)
{
    __shared__ float2 bufA[4][256];
    __shared__ float2 bufB[4][256];
    const int lane = threadIdx.x & 63;
    const int wid  = threadIdx.x >> 6;
    const int row  = (blockIdx.x << 2) | wid;
    float2* A  = bufA[wid];
    float2* Bb = bufB[wid];

    float c0,s0,c1,s1,c2,s2;
    {
        const float k = 6.283185307179586f / 256.f;
        sincosf(k * (float)lane,          &s0, &c0);
        sincosf(k * (float)(lane & ~3),   &s1, &c1);
        sincosf(k * (float)(lane & ~15),  &s2, &c2);
    }

    float h[4];
    #pragma unroll
    for (int j = 0; j < 4; ++j) {
        int col = lane + 64*j;
        float v = t[(size_t)row * DH + col];
        v = g1[col] * (v - st1[col]) * st1[DH + col] + be1[col];
        h[j] = fmaxf(v, 0.f);
    }

    for (int sg = 0; sg < NSEG; ++sg) {
        const float ac = alphas[sg], bc = betas[sg];

        float nn = fmaf(h[0],h[0], fmaf(h[1],h[1], fmaf(h[2],h[2], h[3]*h[3])));
        nn = wave_sum(nn);
        float n  = sqrtf(nn);
        float sn = fminf(fmaxf(SCRT*n, 1e-12f), 1.f - 1e-5f);
        float lam = atanhf(sn) / sn;

        float2 X[4];
        #pragma unroll
        for (int r2 = 0; r2 < 4; ++r2) X[r2] = make_float2(lam*h[r2], 0.f);

        fft_stage0<true>(X, A, lane, c0, s0);
        fft_stage_lds<1,true>(A, Bb, lane, c1, s1);
        fft_stage_lds<2,true>(Bb, A, lane, c2, s2);
        fft_stage3<true>(A, X, lane);

        #pragma unroll
        for (int r2 = 0; r2 < 4; ++r2)
            X[r2] = cmul(X[r2], Heff[sg*DH + lane + 64*r2]);

        fft_stage0<false>(X, A, lane, c0, s0);
        fft_stage_lds<1,false>(A, Bb, lane, c1, s1);
        fft_stage_lds<2,false>(Bb, A, lane, c2, s2);
        fft_stage3<false>(A, X, lane);

        float v0 = X[0].x * (1.f/256.f);
        float v1 = X[1].x * (1.f/256.f);
        float v2 = X[2].x * (1.f/256.f);
        float v3 = X[3].x * (1.f/256.f);
        float nv = fmaf(v0,v0, fmaf(v1,v1, fmaf(v2,v2, v3*v3)));
        nv = wave_sum(nv);
        float n2  = sqrtf(nv);
        float sn2 = fmaxf(SCRT*n2, 1e-12f);
        float mu  = tanhf(sn2) / sn2;
        float am  = ac * mu;
        h[0] = fmaf(am, v0, bc*h[0]);
        h[1] = fmaf(am, v1, bc*h[1]);
        h[2] = fmaf(am, v2, bc*h[2]);
        h[3] = fmaf(am, v3, bc*h[3]);
    }

    #pragma unroll
    for (int j = 0; j < 4; ++j)
        t[(size_t)row * DH + lane + 64*j] = h[j];
}

// ---------------- final: out = relu(bn2(h)) @ W2 + b2 ----------------
__global__ __launch_bounds__(256) void final_kernel(
    const float* __restrict__ t, const float* __restrict__ st2,
    const float* __restrict__ g2, const float* __restrict__ be2,
    const float* __restrict__ W2, const float* __restrict__ b2,
    float* __restrict__ out)
{
    __shared__ __attribute__((aligned(16))) float Hs[16][260];
    __shared__ float W2s[DH*DOUT];
    __shared__ float b2s[16];
    const int tid = threadIdx.x;
    for (int idx = tid; idx < DH*DOUT; idx += 256) W2s[idx] = W2[idx];
    if (tid < DOUT) b2s[tid] = b2[tid];
    const int r0 = blockIdx.x * 16;
    for (int idx = tid; idx < 16*(DH/4); idx += 256) {
        int r  = idx >> 6;
        int c4 = (idx & 63) << 2;
        float4 v = *(const float4*)&t[(size_t)(r0 + r)*DH + c4];
        float o[4] = {v.x, v.y, v.z, v.w};
        #pragma unroll
        for (int k = 0; k < 4; ++k) {
            int c = c4 + k;
            float w = g2[c] * (o[k] - st2[c]) * st2[DH+c] + be2[c];
            o[k] = fmaxf(w, 0.f);
        }
        float4 ov = make_float4(o[0], o[1], o[2], o[3]);
        *(float4*)&Hs[r][c4] = ov;
    }
    __syncthreads();
    if (tid < 16*DOUT) {
        int r = tid / DOUT, j = tid - DOUT*r;
        float acc = b2s[j];
        for (int k = 0; k < DH; ++k)
            acc = fmaf(Hs[r][k], W2s[k*DOUT + j], acc);
        out[(size_t)(r0 + r)*DOUT + j] = acc;
    }
}

// ---------------- launch ----------------
extern "C" void kernel_launch(void* const* d_in, const int* in_sizes, int n_in,
                              void* d_out, int out_size, void* d_ws, size_t ws_size,
                              hipStream_t stream) {
    const float* x      = (const float*)d_in[0];
    const float* W1     = (const float*)d_in[1];
    const float* b1     = (const float*)d_in[2];
    const float* g1     = (const float*)d_in[3];
    const float* be1    = (const float*)d_in[4];
    const float* Hr     = (const float*)d_in[5];
    const float* Hi     = (const float*)d_in[6];
    const float* alphas = (const float*)d_in[7];
    const float* betas  = (const float*)d_in[8];
    const float* g2     = (const float*)d_in[9];
    const float* be2    = (const float*)d_in[10];
    const float* W2     = (const float*)d_in[11];
    const float* b2     = (const float*)d_in[12];
    float* out = (float*)d_out;

    float*  t    = (float*)d_ws;
    float2* Heff = (float2*)((char*)d_ws + (size_t)NB*DH*4);
    float*  st1  = (float*)((char*)Heff + (size_t)NSEG*DH*8);
    float*  st2  = st1 + 512;

    prep_kernel<<<1, 256, 0, stream>>>(Hr, Hi, Heff, st1);
    gemm1_kernel<<<dim3(NB/64, DH/64), 256, 0, stream>>>(x, W1, b1, t);
    colstats_kernel<<<256, 256, 0, stream>>>(t, st1, st1+DH);
    finalize_kernel<<<1, 256, 0, stream>>>(st1);
    seg_kernel<<<NB/4, 256, 0, stream>>>(t, Heff, st1, g1, be1, alphas, betas);
    colstats_kernel<<<256, 256, 0, stream>>>(t, st2, st2+DH);
    finalize_kernel<<<1, 256, 0, stream>>>(st2);
    final_kernel<<<NB/16, 256, 0, stream>>>(t, st2, g2, be2, W2, b2, out);
}

// Round 3
// 938.066 us; speedup vs baseline: 1.0230x; 1.0230x over previous
//
#include <hip/hip_runtime.h>
#include <math.h>

#define NB     32768
#define DH     256
#define DIN    784
#define DOUT   10
#define NSEG   20
#define EPSBN  1e-5f
#define SCRT   0.031622776601683794f   // sqrt(0.001)
#define PI_D   3.14159265358979323846

typedef _Float16 h16;
typedef _Float16 f16x8 __attribute__((ext_vector_type(8)));
typedef float    f32x4 __attribute__((ext_vector_type(4)));

// ---------- helpers ----------
__device__ __forceinline__ void gl_lds16(const void* g, void* l){
  __builtin_amdgcn_global_load_lds(
      (const __attribute__((address_space(1))) unsigned int*)g,
      (__attribute__((address_space(3))) unsigned int*)l, 16, 0, 0);
}
// stage a 32KB tile: 4 waves x 8 issues x 64 lanes x 16B
__device__ __forceinline__ void stageB32K(const char* src, char* ldsbase, int wid, int lane){
  #pragma unroll
  for (int q = 0; q < 8; ++q)
    gl_lds16(src + wid*8192 + q*1024 + lane*16, ldsbase + wid*8192 + q*1024);
}
// A LDS [64 rows][256 k] fp16, 512B/row, XOR-swizzled 16B slots
__device__ __forceinline__ int abyte(int row, int kcol){
  return row*512 + ((kcol*2) ^ ((row & 7) << 4));
}

// ---------- prep: H^50 -> g = Re(ifft(H^50)) (fp64), zero BN stats ----------
__global__ void prep_g(const float* __restrict__ Hr, const float* __restrict__ Hi,
                       double* __restrict__ g_re, float* __restrict__ st1, float* __restrict__ st2)
{
  __shared__ double cT[256], sT[256], HrE[256], HiE[256];
  int tid = threadIdx.x, s = blockIdx.x;
  double th = (2.0 * PI_D / 256.0) * (double)tid;
  double sv, cv; sincos(th, &sv, &cv);
  cT[tid] = cv; sT[tid] = sv;
  double ar = (double)Hr[s*256 + tid], ai = (double)Hi[s*256 + tid];
  double pr = 1.0, pi = 0.0;
  for (int k = 0; k < 50; ++k){ double nr = pr*ar - pi*ai; pi = pr*ai + pi*ar; pr = nr; }
  HrE[tid] = pr; HiE[tid] = pi;
  if (s == 0){ st1[tid] = 0.f; st1[256+tid] = 0.f; st2[tid] = 0.f; st2[256+tid] = 0.f; }
  __syncthreads();
  double acc = 0.0;
  for (int k = 0; k < 256; ++k){
    int idx = (k * tid) & 255;
    acc += HrE[k]*cT[idx] - HiE[k]*sT[idx];
  }
  g_re[s*256 + tid] = acc * (1.0/256.0);
}

// ---------- pack circulant B tiles: per (seg, chunk) a 32KB swizzled LDS image ----------
// chunk 0-3: hi fp16 of M[k][n], k = ch*64 + k2 ; chunk 4-7: lo fp16, k = (ch-4)*64 + k2
// image byte for logical (n, k2): n*128 + ((k2*2) ^ ((n&7)<<4))
// FIX (R2): one thread per row n, full 128-byte row coverage (R1 wrote only half the image).
__global__ void prep_packB(const double* __restrict__ g_re, char* __restrict__ wsB)
{
  int blk = blockIdx.x; int s = blk >> 3, ch = blk & 7;
  int n = threadIdx.x;                  // 0..255
  const double* g = g_re + s*256;
  char* out = wsB + (size_t)blk * 32768;
  int xr = (n & 7) << 4;
  #pragma unroll
  for (int j = 0; j < 64; ++j){
    int w  = 2*j;
    int k2 = (w ^ xr) >> 1;
    int k  = (ch & 3)*64 + k2;
    int d  = (n - k) & 255;
    float v = (float)g[d];
    h16 hv = (h16)v;
    h16 ov = (ch < 4) ? hv : (h16)(v - (float)hv);
    *(h16*)(out + n*128 + w) = ov;
  }
}

// ---------- pack W1 tiles: 25 k-chunks x {hi,lo}, each [256 n][32 k] fp16 swizzled ----------
// image byte for (n,k2): n*64 + ((k2*2) ^ ((n&3)<<4)); k = ch*32+k2, zero-padded past 784
__global__ void prep_packW(const float* __restrict__ W1, char* __restrict__ wsW)
{
  int blk = blockIdx.x; int ch = blk >> 1, lo = blk & 1;
  int n = threadIdx.x;
  char* out = wsW + (size_t)ch*32768 + lo*16384;
  int xr = (n & 3) << 4;
  #pragma unroll
  for (int j = 0; j < 32; ++j){
    int w  = 2*j;
    int k2 = (w ^ xr) >> 1;
    int k  = ch*32 + k2;
    float v = (k < 784) ? W1[(size_t)k*256 + n] : 0.f;
    h16 hv = (h16)v;
    h16 ov = lo ? (h16)(v - (float)hv) : hv;
    *(h16*)(out + n*64 + w) = ov;
  }
}

// ---------- GEMM1: t = x @ W1 via fp16 3-term split MFMA (bias b1 cancels through BN1) ----------
__global__ __launch_bounds__(256) void gemm1_mfma(const float* __restrict__ x,
                                                  const char* __restrict__ wsW,
                                                  float* __restrict__ t)
{
  __shared__ __attribute__((aligned(16))) char BB[2][32768]; // hi 16K + lo 16K
  __shared__ __attribute__((aligned(16))) char AB[2][8192];  // hi 4K + lo 4K
  const int tid = threadIdx.x;
  const int lane = tid & 63, wid = tid >> 6;
  const int cl = lane & 15, g4 = lane >> 4;
  const int brow = blockIdx.x * 64;
  const int nb0 = wid * 64;
  const int arow = tid & 63, kq = tid >> 6;

  f32x4 zz = {0.f,0.f,0.f,0.f};
  f32x4 acc[4][4];
  #pragma unroll
  for (int i = 0; i < 4; ++i)
    #pragma unroll
    for (int j = 0; j < 4; ++j) acc[i][j] = zz;

  float4 a0, a1;
  const float4 z4 = make_float4(0.f,0.f,0.f,0.f);

  // prologue: stage chunk 0
  stageB32K(wsW, BB[0], wid, lane);
  {
    int k0 = kq*8;
    const float* p = x + (size_t)(brow + arow)*784 + k0;
    a0 = *(const float4*)p; a1 = *(const float4*)(p + 4);
    f16x8 hv, lv;
    float vv[8] = {a0.x,a0.y,a0.z,a0.w,a1.x,a1.y,a1.z,a1.w};
    #pragma unroll
    for (int j = 0; j < 8; ++j){ h16 hh = (h16)vv[j]; hv[j] = hh; lv[j] = (h16)(vv[j] - (float)hh); }
    int aoff = arow*64 + 16*(kq ^ (arow & 3));
    *(f16x8*)(AB[0] + aoff) = hv;
    *(f16x8*)(AB[0] + 4096 + aoff) = lv;
  }
  __syncthreads();

  int cur = 0;
  for (int ch = 0; ch < 25; ++ch){
    float4 n0 = z4, n1 = z4;
    bool have_next = (ch < 24);
    if (have_next){
      stageB32K(wsW + (size_t)(ch+1)*32768, BB[cur^1], wid, lane);
      int k0 = (ch+1)*32 + kq*8;
      if (k0 + 7 < 784){
        const float* p = x + (size_t)(brow + arow)*784 + k0;
        n0 = *(const float4*)p; n1 = *(const float4*)(p + 4);
      }
    }
    // compute chunk ch
    const char* Bc = BB[cur];
    const char* Ac = AB[cur];
    f16x8 bh[4], bl[4], ah[4], al[4];
    #pragma unroll
    for (int ni = 0; ni < 4; ++ni){
      int n = nb0 + ni*16 + cl;
      int boff = n*64 + 16*(g4 ^ (n & 3));
      bh[ni] = *(const f16x8*)(Bc + boff);
      bl[ni] = *(const f16x8*)(Bc + 16384 + boff);
    }
    #pragma unroll
    for (int mi = 0; mi < 4; ++mi){
      int row = mi*16 + cl;
      int aoff = row*64 + 16*(g4 ^ (row & 3));
      ah[mi] = *(const f16x8*)(Ac + aoff);
      al[mi] = *(const f16x8*)(Ac + 4096 + aoff);
    }
    #pragma unroll
    for (int mi = 0; mi < 4; ++mi)
      #pragma unroll
      for (int ni = 0; ni < 4; ++ni){
        acc[mi][ni] = __builtin_amdgcn_mfma_f32_16x16x32_f16(ah[mi], bh[ni], acc[mi][ni], 0,0,0);
        acc[mi][ni] = __builtin_amdgcn_mfma_f32_16x16x32_f16(al[mi], bh[ni], acc[mi][ni], 0,0,0);
        acc[mi][ni] = __builtin_amdgcn_mfma_f32_16x16x32_f16(ah[mi], bl[ni], acc[mi][ni], 0,0,0);
      }
    if (have_next){
      f16x8 hv, lv;
      float vv[8] = {n0.x,n0.y,n0.z,n0.w,n1.x,n1.y,n1.z,n1.w};
      #pragma unroll
      for (int j = 0; j < 8; ++j){ h16 hh = (h16)vv[j]; hv[j] = hh; lv[j] = (h16)(vv[j] - (float)hh); }
      int aoff = arow*64 + 16*(kq ^ (arow & 3));
      *(f16x8*)(AB[cur^1] + aoff) = hv;
      *(f16x8*)(AB[cur^1] + 4096 + aoff) = lv;
      __syncthreads();
      cur ^= 1;
    }
  }
  // store
  #pragma unroll
  for (int mi = 0; mi < 4; ++mi)
    #pragma unroll
    for (int ni = 0; ni < 4; ++ni)
      #pragma unroll
      for (int r = 0; r < 4; ++r){
        int row = brow + mi*16 + g4*4 + r;
        int col = nb0 + ni*16 + cl;
        t[(size_t)row*256 + col] = acc[mi][ni][r];
      }
}

// ---------- column stats ----------
__global__ __launch_bounds__(256) void colstats_kernel(const float* __restrict__ t,
                                                       float* __restrict__ sum,
                                                       float* __restrict__ ssq)
{
  const int col = threadIdx.x;
  float s = 0.f, q = 0.f;
  for (int r = blockIdx.x; r < NB; r += gridDim.x){
    float v = t[(size_t)r * DH + col];
    s += v; q = fmaf(v, v, q);
  }
  atomicAdd(&sum[col], s);
  atomicAdd(&ssq[col], q);
}

__global__ void finalize_kernel(float* __restrict__ st)
{
  int j = threadIdx.x;
  float mu = st[j] * (1.f/(float)NB);
  float var = st[DH+j] * (1.f/(float)NB) - mu*mu;
  st[j] = mu;
  st[DH+j] = rsqrtf(var + EPSBN);
}

// ---------- seg epilogue tail: write A hi/lo from h regs, reduce ||h||^2 -> nh2s ----------
__device__ __forceinline__ void writeA_reduce(float (&h)[4][4][4], char* Ahi, char* Alo,
                                              float (*red)[4], float* nh2s,
                                              int cl, int g4, int wid, int nb0, int lane)
{
  float ph[4][4];
  #pragma unroll
  for (int mi = 0; mi < 4; ++mi)
    #pragma unroll
    for (int r = 0; r < 4; ++r) ph[mi][r] = 0.f;
  #pragma unroll
  for (int mi = 0; mi < 4; ++mi)
    #pragma unroll
    for (int ni = 0; ni < 4; ++ni)
      #pragma unroll
      for (int r = 0; r < 4; ++r){
        int row = mi*16 + g4*4 + r;
        int col = nb0 + ni*16 + cl;
        float hv = h[mi][ni][r];
        h16 hh = (h16)hv;
        h16 hl = (h16)(hv - (float)hh);
        *(h16*)(Ahi + abyte(row, col)) = hh;
        *(h16*)(Alo + abyte(row, col)) = hl;
        ph[mi][r] = fmaf(hv, hv, ph[mi][r]);
      }
  #pragma unroll
  for (int m = 1; m < 16; m <<= 1)
    #pragma unroll
    for (int mi = 0; mi < 4; ++mi)
      #pragma unroll
      for (int r = 0; r < 4; ++r)
        ph[mi][r] += __shfl_xor(ph[mi][r], m, 64);
  float val = 0.f;
  #pragma unroll
  for (int mi = 0; mi < 4; ++mi)
    #pragma unroll
    for (int r = 0; r < 4; ++r)
      if (cl == mi*4 + r) val = ph[mi][r];
  red[(cl>>2)*16 + g4*4 + (cl&3)][wid] = val;
  __syncthreads();
  if (wid == 0){
    f32x4 rv = *(const f32x4*)&red[lane][0];
    nh2s[lane] = rv[0] + rv[1] + rv[2] + rv[3];
  }
  __syncthreads();
}

// ---------- persistent segment kernel: BN1+relu, 20x (norm-scaled circulant matmul) ----------
__global__ __launch_bounds__(256) void seg_mfma(
    float* __restrict__ t, const char* __restrict__ wsB,
    const float* __restrict__ st1,
    const float* __restrict__ g1, const float* __restrict__ be1,
    const float* __restrict__ alphas, const float* __restrict__ betas)
{
  __shared__ __attribute__((aligned(16))) char Ahi[32768];
  __shared__ __attribute__((aligned(16))) char Alo[32768];
  __shared__ __attribute__((aligned(16))) char BB[2][32768];
  __shared__ __attribute__((aligned(16))) float red[64][4];
  __shared__ __attribute__((aligned(16))) float scal[64];
  __shared__ float nh2s[64];

  const int tid = threadIdx.x;
  const int lane = tid & 63, wid = tid >> 6;
  const int cl = lane & 15, g4 = lane >> 4;
  const int brow = blockIdx.x * 64;
  const int nb0 = wid * 64;

  // stage segment 0 chunk 0 early
  stageB32K(wsB, BB[0], wid, lane);

  // init: load t, BN1 + relu -> h regs
  float h[4][4][4];
  {
    float mu[4], rs[4], gg[4], bb[4];
    #pragma unroll
    for (int ni = 0; ni < 4; ++ni){
      int col = nb0 + ni*16 + cl;
      mu[ni] = st1[col]; rs[ni] = st1[256+col]; gg[ni] = g1[col]; bb[ni] = be1[col];
    }
    #pragma unroll
    for (int mi = 0; mi < 4; ++mi)
      #pragma unroll
      for (int ni = 0; ni < 4; ++ni)
        #pragma unroll
        for (int r = 0; r < 4; ++r){
          int row = brow + mi*16 + g4*4 + r;
          int col = nb0 + ni*16 + cl;
          float v = t[(size_t)row*256 + col];
          v = gg[ni]*(v - mu[ni])*rs[ni] + bb[ni];
          h[mi][ni][r] = fmaxf(v, 0.f);
        }
  }
  writeA_reduce(h, Ahi, Alo, red, nh2s, cl, g4, wid, nb0, lane);

  int cur = 0;
  for (int sg = 0; sg < NSEG; ++sg){
    const float al = alphas[sg], bt = betas[sg];
    f32x4 zz = {0.f,0.f,0.f,0.f};
    f32x4 acc[4][4];
    #pragma unroll
    for (int i = 0; i < 4; ++i)
      #pragma unroll
      for (int j = 0; j < 4; ++j) acc[i][j] = zz;

    for (int ch = 0; ch < 8; ++ch){
      int nxt = sg*8 + ch + 1;
      if (nxt < NSEG*8) stageB32K(wsB + (size_t)nxt*32768, BB[cur^1], wid, lane);
      const char* Bc = BB[cur];
      const bool hiCh = (ch < 4);
      const int kb = (ch & 3) * 64;
      #pragma unroll
      for (int half = 0; half < 2; ++half){
        const int kk = half * 32;
        f16x8 bf[4];
        #pragma unroll
        for (int ni = 0; ni < 4; ++ni){
          int n = nb0 + ni*16 + cl;
          bf[ni] = *(const f16x8*)(Bc + n*128 + (((kk + g4*8)*2) ^ ((n & 7) << 4)));
        }
        f16x8 af[4];
        #pragma unroll
        for (int mi = 0; mi < 4; ++mi)
          af[mi] = *(const f16x8*)(Ahi + abyte(mi*16 + cl, kb + kk + g4*8));
        #pragma unroll
        for (int mi = 0; mi < 4; ++mi)
          #pragma unroll
          for (int ni = 0; ni < 4; ++ni)
            acc[mi][ni] = __builtin_amdgcn_mfma_f32_16x16x32_f16(af[mi], bf[ni], acc[mi][ni], 0,0,0);
        if (hiCh){
          #pragma unroll
          for (int mi = 0; mi < 4; ++mi)
            af[mi] = *(const f16x8*)(Alo + abyte(mi*16 + cl, kb + kk + g4*8));
          #pragma unroll
          for (int mi = 0; mi < 4; ++mi)
            #pragma unroll
            for (int ni = 0; ni < 4; ++ni)
              acc[mi][ni] = __builtin_amdgcn_mfma_f32_16x16x32_f16(af[mi], bf[ni], acc[mi][ni], 0,0,0);
        }
      }
      __syncthreads();
      cur ^= 1;
    }

    // epilogue: row norms of w, scalars, update h, rewrite A
    {
      float p[4][4];
      #pragma unroll
      for (int mi = 0; mi < 4; ++mi)
        #pragma unroll
        for (int r = 0; r < 4; ++r){
          float s = 0.f;
          #pragma unroll
          for (int ni = 0; ni < 4; ++ni){ float w = acc[mi][ni][r]; s = fmaf(w, w, s); }
          p[mi][r] = s;
        }
      #pragma unroll
      for (int m = 1; m < 16; m <<= 1)
        #pragma unroll
        for (int mi = 0; mi < 4; ++mi)
          #pragma unroll
          for (int r = 0; r < 4; ++r)
            p[mi][r] += __shfl_xor(p[mi][r], m, 64);
      float val = 0.f;
      #pragma unroll
      for (int mi = 0; mi < 4; ++mi)
        #pragma unroll
        for (int r = 0; r < 4; ++r)
          if (cl == mi*4 + r) val = p[mi][r];
      red[(cl>>2)*16 + g4*4 + (cl&3)][wid] = val;
      __syncthreads();
      if (wid == 0){
        f32x4 rv = *(const f32x4*)&red[lane][0];
        float nw2 = rv[0] + rv[1] + rv[2] + rv[3];
        float nh  = sqrtf(nh2s[lane]);
        float snh = fminf(fmaxf(SCRT*nh, 1e-12f), 1.f - 1e-5f);
        float lam = atanhf(snh) / snh;
        float nv  = lam * sqrtf(nw2);
        float snv = fmaxf(SCRT*nv, 1e-12f);
        float muv = tanhf(snv) / snv;
        scal[lane] = al * muv * lam;
      }
      __syncthreads();
      #pragma unroll
      for (int mi = 0; mi < 4; ++mi){
        f32x4 sv = *(const f32x4*)&scal[mi*16 + g4*4];
        #pragma unroll
        for (int r = 0; r < 4; ++r)
          #pragma unroll
          for (int ni = 0; ni < 4; ++ni)
            h[mi][ni][r] = fmaf(sv[r], acc[mi][ni][r], bt * h[mi][ni][r]);
      }
      writeA_reduce(h, Ahi, Alo, red, nh2s, cl, g4, wid, nb0, lane);
    }
  }

  // store h back to t
  #pragma unroll
  for (int mi = 0; mi < 4; ++mi)
    #pragma unroll
    for (int ni = 0; ni < 4; ++ni)
      #pragma unroll
      for (int r = 0; r < 4; ++r){
        int row = brow + mi*16 + g4*4 + r;
        int col = nb0 + ni*16 + cl;
        t[(size_t)row*256 + col] = h[mi][ni][r];
      }
}

// ---------- final: out = relu(bn2(h)) @ W2 + b2 ----------
__global__ __launch_bounds__(256) void final_kernel(
    const float* __restrict__ t, const float* __restrict__ st2,
    const float* __restrict__ g2, const float* __restrict__ be2,
    const float* __restrict__ W2, const float* __restrict__ b2,
    float* __restrict__ out)
{
  __shared__ __attribute__((aligned(16))) float Hs[16][260];
  __shared__ float W2s[DH*DOUT];
  __shared__ float b2s[16];
  const int tid = threadIdx.x;
  for (int idx = tid; idx < DH*DOUT; idx += 256) W2s[idx] = W2[idx];
  if (tid < DOUT) b2s[tid] = b2[tid];
  const int r0 = blockIdx.x * 16;
  for (int idx = tid; idx < 16*(DH/4); idx += 256) {
    int r  = idx >> 6;
    int c4 = (idx & 63) << 2;
    float4 v = *(const float4*)&t[(size_t)(r0 + r)*DH + c4];
    float o[4] = {v.x, v.y, v.z, v.w};
    #pragma unroll
    for (int k = 0; k < 4; ++k) {
      int c = c4 + k;
      float w = g2[c] * (o[k] - st2[c]) * st2[DH+c] + be2[c];
      o[k] = fmaxf(w, 0.f);
    }
    *(float4*)&Hs[r][c4] = make_float4(o[0], o[1], o[2], o[3]);
  }
  __syncthreads();
  if (tid < 16*DOUT) {
    int r = tid / DOUT, j = tid - DOUT*r;
    float acc = b2s[j];
    for (int k = 0; k < DH; ++k)
      acc = fmaf(Hs[r][k], W2s[k*DOUT + j], acc);
    out[(size_t)(r0 + r)*DOUT + j] = acc;
  }
}

// ---------- launch ----------
extern "C" void kernel_launch(void* const* d_in, const int* in_sizes, int n_in,
                              void* d_out, int out_size, void* d_ws, size_t ws_size,
                              hipStream_t stream) {
  const float* x      = (const float*)d_in[0];
  const float* W1     = (const float*)d_in[1];
  // d_in[2] = b1 (cancels through BN1)
  const float* g1     = (const float*)d_in[3];
  const float* be1    = (const float*)d_in[4];
  const float* Hr     = (const float*)d_in[5];
  const float* Hi     = (const float*)d_in[6];
  const float* alphas = (const float*)d_in[7];
  const float* betas  = (const float*)d_in[8];
  const float* g2     = (const float*)d_in[9];
  const float* be2    = (const float*)d_in[10];
  const float* W2     = (const float*)d_in[11];
  const float* b2     = (const float*)d_in[12];
  float* out = (float*)d_out;

  char* ws = (char*)d_ws;
  float*  t    = (float*)(ws);                                   // 33,554,432 B
  char*   wsB  = ws + 33554432;                                  //  5,242,880 B
  char*   wsW  = ws + 38797312;                                  //    819,200 B
  float*  st1  = (float*)(ws + 39616512);                        //      2,048 B
  float*  st2  = (float*)(ws + 39618560);                        //      2,048 B
  double* g_re = (double*)(ws + 39620608);                       //     40,960 B

  prep_g   <<<NSEG, 256, 0, stream>>>(Hr, Hi, g_re, st1, st2);
  prep_packB<<<NSEG*8, 256, 0, stream>>>(g_re, wsB);
  prep_packW<<<50, 256, 0, stream>>>(W1, wsW);
  gemm1_mfma<<<NB/64, 256, 0, stream>>>(x, wsW, t);
  colstats_kernel<<<256, 256, 0, stream>>>(t, st1, st1 + DH);
  finalize_kernel<<<1, 256, 0, stream>>>(st1);
  seg_mfma <<<NB/64, 256, 0, stream>>>(t, wsB, st1, g1, be1, alphas, betas);
  colstats_kernel<<<256, 256, 0, stream>>>(t, st2, st2 + DH);
  finalize_kernel<<<1, 256, 0, stream>>>(st2);
  final_kernel<<<NB/16, 256, 0, stream>>>(t, st2, g2, be2, W2, b2, out);
}

// Round 4
// 561.553 us; speedup vs baseline: 1.7089x; 1.6705x over previous
//
#include <hip/hip_runtime.h>
#include <math.h>

#define NB     32768
#define DH     256
#define DIN    784
#define DOUT   10
#define NSEG   20
#define EPSBN  1e-5f
#define SCRT   0.031622776601683794f   // sqrt(0.001)
#define PI_D   3.14159265358979323846

typedef _Float16 h16;
typedef _Float16 f16x8 __attribute__((ext_vector_type(8)));
typedef float    f32x4 __attribute__((ext_vector_type(4)));

// ---------- helpers ----------
__device__ __forceinline__ void gl_lds16(const void* g, void* l){
  __builtin_amdgcn_global_load_lds(
      (const __attribute__((address_space(1))) unsigned int*)g,
      (__attribute__((address_space(3))) unsigned int*)l, 16, 0, 0);
}
__device__ __forceinline__ void stageB32K(const char* src, char* ldsbase, int wid, int lane){
  #pragma unroll
  for (int q = 0; q < 8; ++q)
    gl_lds16(src + wid*8192 + q*1024 + lane*16, ldsbase + wid*8192 + q*1024);
}

__device__ __forceinline__ float2 cmul(float2 a, float2 b) {
    return make_float2(fmaf(a.x, b.x, -(a.y*b.y)), fmaf(a.x, b.y, a.y*b.x));
}
__device__ __forceinline__ float2 cadd(float2 a, float2 b){ return make_float2(a.x+b.x, a.y+b.y); }
__device__ __forceinline__ float2 csub(float2 a, float2 b){ return make_float2(a.x-b.x, a.y-b.y); }
__device__ __forceinline__ int physi(int i){ return i ^ ((i >> 4) & 15); }  // bijective LDS swizzle

// ---------- prep: Heff = H^50 (fp64) -> G[k] = (Heff[k]+conj(Heff[-k]))/2 ; zero BN stats ----------
__global__ void prep_G(const float* __restrict__ Hr, const float* __restrict__ Hi,
                       float2* __restrict__ Gt, float* __restrict__ st1, float* __restrict__ st2)
{
  __shared__ double HrE[256], HiE[256];
  int k = threadIdx.x, s = blockIdx.x;
  double ar = (double)Hr[s*256 + k], ai = (double)Hi[s*256 + k];
  double pr = 1.0, pi = 0.0;
  for (int i = 0; i < 50; ++i){ double nr = pr*ar - pi*ai; pi = pr*ai + pi*ar; pr = nr; }
  HrE[k] = pr; HiE[k] = pi;
  if (s == 0){ st1[k] = 0.f; st1[256+k] = 0.f; st2[k] = 0.f; st2[256+k] = 0.f; }
  __syncthreads();
  int km = (256 - k) & 255;
  float gr = (float)(0.5 * (HrE[k] + HrE[km]));
  float gi = (float)(0.5 * (HiE[k] - HiE[km]));
  Gt[s*256 + k] = make_float2(gr, gi);
}

// ---------- pack W1 tiles: 25 k-chunks x {hi,lo}, each [256 n][32 k] fp16 swizzled ----------
__global__ void prep_packW(const float* __restrict__ W1, char* __restrict__ wsW)
{
  int blk = blockIdx.x; int ch = blk >> 1, lo = blk & 1;
  int n = threadIdx.x;
  char* out = wsW + (size_t)ch*32768 + lo*16384;
  int xr = (n & 3) << 4;
  #pragma unroll
  for (int j = 0; j < 32; ++j){
    int w  = 2*j;
    int k2 = (w ^ xr) >> 1;
    int k  = ch*32 + k2;
    float v = (k < 784) ? W1[(size_t)k*256 + n] : 0.f;
    h16 hv = (h16)v;
    h16 ov = lo ? (h16)(v - (float)hv) : hv;
    *(h16*)(out + n*64 + w) = ov;
  }
}

// ---------- GEMM1: t = x @ W1 via fp16 3-term split MFMA (b1 cancels through BN1) ----------
__global__ __launch_bounds__(256) void gemm1_mfma(const float* __restrict__ x,
                                                  const char* __restrict__ wsW,
                                                  float* __restrict__ t)
{
  __shared__ __attribute__((aligned(16))) char BB[2][32768]; // hi 16K + lo 16K
  __shared__ __attribute__((aligned(16))) char AB[2][8192];  // hi 4K + lo 4K
  const int tid = threadIdx.x;
  const int lane = tid & 63, wid = tid >> 6;
  const int cl = lane & 15, g4 = lane >> 4;
  const int brow = blockIdx.x * 64;
  const int nb0 = wid * 64;
  const int arow = tid & 63, kq = tid >> 6;

  f32x4 zz = {0.f,0.f,0.f,0.f};
  f32x4 acc[4][4];
  #pragma unroll
  for (int i = 0; i < 4; ++i)
    #pragma unroll
    for (int j = 0; j < 4; ++j) acc[i][j] = zz;

  float4 a0, a1;
  const float4 z4 = make_float4(0.f,0.f,0.f,0.f);

  stageB32K(wsW, BB[0], wid, lane);
  {
    int k0 = kq*8;
    const float* p = x + (size_t)(brow + arow)*784 + k0;
    a0 = *(const float4*)p; a1 = *(const float4*)(p + 4);
    f16x8 hv, lv;
    float vv[8] = {a0.x,a0.y,a0.z,a0.w,a1.x,a1.y,a1.z,a1.w};
    #pragma unroll
    for (int j = 0; j < 8; ++j){ h16 hh = (h16)vv[j]; hv[j] = hh; lv[j] = (h16)(vv[j] - (float)hh); }
    int aoff = arow*64 + 16*(kq ^ (arow & 3));
    *(f16x8*)(AB[0] + aoff) = hv;
    *(f16x8*)(AB[0] + 4096 + aoff) = lv;
  }
  __syncthreads();

  int cur = 0;
  for (int ch = 0; ch < 25; ++ch){
    float4 n0 = z4, n1 = z4;
    bool have_next = (ch < 24);
    if (have_next){
      stageB32K(wsW + (size_t)(ch+1)*32768, BB[cur^1], wid, lane);
      int k0 = (ch+1)*32 + kq*8;
      if (k0 + 7 < 784){
        const float* p = x + (size_t)(brow + arow)*784 + k0;
        n0 = *(const float4*)p; n1 = *(const float4*)(p + 4);
      }
    }
    const char* Bc = BB[cur];
    const char* Ac = AB[cur];
    f16x8 bh[4], bl[4], ah[4], al[4];
    #pragma unroll
    for (int ni = 0; ni < 4; ++ni){
      int n = nb0 + ni*16 + cl;
      int boff = n*64 + 16*(g4 ^ (n & 3));
      bh[ni] = *(const f16x8*)(Bc + boff);
      bl[ni] = *(const f16x8*)(Bc + 16384 + boff);
    }
    #pragma unroll
    for (int mi = 0; mi < 4; ++mi){
      int row = mi*16 + cl;
      int aoff = row*64 + 16*(g4 ^ (row & 3));
      ah[mi] = *(const f16x8*)(Ac + aoff);
      al[mi] = *(const f16x8*)(Ac + 4096 + aoff);
    }
    #pragma unroll
    for (int mi = 0; mi < 4; ++mi)
      #pragma unroll
      for (int ni = 0; ni < 4; ++ni){
        acc[mi][ni] = __builtin_amdgcn_mfma_f32_16x16x32_f16(ah[mi], bh[ni], acc[mi][ni], 0,0,0);
        acc[mi][ni] = __builtin_amdgcn_mfma_f32_16x16x32_f16(al[mi], bh[ni], acc[mi][ni], 0,0,0);
        acc[mi][ni] = __builtin_amdgcn_mfma_f32_16x16x32_f16(ah[mi], bl[ni], acc[mi][ni], 0,0,0);
      }
    if (have_next){
      f16x8 hv, lv;
      float vv[8] = {n0.x,n0.y,n0.z,n0.w,n1.x,n1.y,n1.z,n1.w};
      #pragma unroll
      for (int j = 0; j < 8; ++j){ h16 hh = (h16)vv[j]; hv[j] = hh; lv[j] = (h16)(vv[j] - (float)hh); }
      int aoff = arow*64 + 16*(kq ^ (arow & 3));
      *(f16x8*)(AB[cur^1] + aoff) = hv;
      *(f16x8*)(AB[cur^1] + 4096 + aoff) = lv;
      __syncthreads();
      cur ^= 1;
    }
  }
  #pragma unroll
  for (int mi = 0; mi < 4; ++mi)
    #pragma unroll
    for (int ni = 0; ni < 4; ++ni)
      #pragma unroll
      for (int r = 0; r < 4; ++r){
        int row = brow + mi*16 + g4*4 + r;
        int col = nb0 + ni*16 + cl;
        t[(size_t)row*256 + col] = acc[mi][ni][r];
      }
}

// ---------- column stats ----------
__global__ __launch_bounds__(256) void colstats_kernel(const float* __restrict__ t,
                                                       float* __restrict__ sum,
                                                       float* __restrict__ ssq)
{
  const int col = threadIdx.x;
  float s = 0.f, q = 0.f;
  for (int r = blockIdx.x; r < NB; r += gridDim.x){
    float v = t[(size_t)r * DH + col];
    s += v; q = fmaf(v, v, q);
  }
  atomicAdd(&sum[col], s);
  atomicAdd(&ssq[col], q);
}

__global__ void finalize_kernel(float* __restrict__ st)
{
  int j = threadIdx.x;
  float mu = st[j] * (1.f/(float)NB);
  float var = st[DH+j] * (1.f/(float)NB) - mu*mu;
  st[j] = mu;
  st[DH+j] = rsqrtf(var + EPSBN);
}

// ---------- FFT pieces (radix-4 Stockham, N=256, 1 wave per row; validated in R0/R1) ----------
template<bool FWD>
__device__ __forceinline__ void fft_stage0(const float2 X[4], float2* dst, int lane, float wc, float ws)
{
    float2 a=X[0], b=X[1], c=X[2], d=X[3];
    float2 t0 = cadd(a,c), t1 = csub(a,c), t2 = cadd(b,d), bd = csub(b,d);
    float2 t3 = FWD ? make_float2(bd.y, -bd.x) : make_float2(-bd.y, bd.x);
    float2 w1 = make_float2(wc, FWD ? -ws : ws);
    float2 w2 = cmul(w1,w1);
    float2 w3 = cmul(w2,w1);
    int j = lane << 2;
    dst[physi(j)]   = cadd(t0,t2);
    dst[physi(j+1)] = cmul(cadd(t1,t3), w1);
    dst[physi(j+2)] = cmul(csub(t0,t2), w2);
    dst[physi(j+3)] = cmul(csub(t1,t3), w3);
}

template<int TT, bool FWD>
__device__ __forceinline__ void fft_stage_lds(const float2* src, float2* dst, int lane, float wc, float ws)
{
    const int s_ = 1 << (2*TT);
    int i = lane;
    float2 a = src[physi(i)];
    float2 b = src[physi(i+64)];
    float2 c = src[physi(i+128)];
    float2 d = src[physi(i+192)];
    float2 t0 = cadd(a,c), t1 = csub(a,c), t2 = cadd(b,d), bd = csub(b,d);
    float2 t3 = FWD ? make_float2(bd.y, -bd.x) : make_float2(-bd.y, bd.x);
    float2 w1 = make_float2(wc, FWD ? -ws : ws);
    float2 w2 = cmul(w1,w1);
    float2 w3 = cmul(w2,w1);
    int j = i + 3*(i & ~(s_-1));
    dst[physi(j)]      = cadd(t0,t2);
    dst[physi(j+s_)]   = cmul(cadd(t1,t3), w1);
    dst[physi(j+2*s_)] = cmul(csub(t0,t2), w2);
    dst[physi(j+3*s_)] = cmul(csub(t1,t3), w3);
}

template<bool FWD>
__device__ __forceinline__ void fft_stage3(const float2* src, float2 X[4], int lane)
{
    float2 a = src[physi(lane)];
    float2 b = src[physi(lane+64)];
    float2 c = src[physi(lane+128)];
    float2 d = src[physi(lane+192)];
    float2 t0 = cadd(a,c), t1 = csub(a,c), t2 = cadd(b,d), bd = csub(b,d);
    float2 t3 = FWD ? make_float2(bd.y, -bd.x) : make_float2(-bd.y, bd.x);
    X[0] = cadd(t0,t2);
    X[1] = cadd(t1,t3);
    X[2] = csub(t0,t2);
    X[3] = csub(t1,t3);
}

// ---------- segments: ONE fft, 20x diagonal update H *= (s*G + b), ONE ifft ----------
// Circulant diagonalization: v = Re(ifft(fft(u)*Heff)) == filter by G[k]=(Heff[k]+conj(Heff[-k]))/2.
// Norms by Parseval: ||h||^2 = sum|H|^2/256, ||w||^2 = sum|H|^2|G|^2/256 (w = h conv g).
__global__ __launch_bounds__(256) void seg_fft(
    float* __restrict__ t, const float2* __restrict__ Gt,
    const float* __restrict__ st1,
    const float* __restrict__ g1, const float* __restrict__ be1,
    const float* __restrict__ alphas, const float* __restrict__ betas)
{
  __shared__ float2 bufA[4][256];
  __shared__ float2 bufB[4][256];
  const int lane = threadIdx.x & 63;
  const int wid  = threadIdx.x >> 6;
  const int row  = (blockIdx.x << 2) | wid;
  float2* A  = bufA[wid];
  float2* Bb = bufB[wid];

  float c0,s0,c1,s1,c2,s2;
  {
    const float k = 6.283185307179586f / 256.f;
    sincosf(k * (float)lane,          &s0, &c0);
    sincosf(k * (float)(lane & ~3),   &s1, &c1);
    sincosf(k * (float)(lane & ~15),  &s2, &c2);
  }

  // load + BN1 + relu
  float2 X[4];
  #pragma unroll
  for (int j = 0; j < 4; ++j) {
    int col = lane + 64*j;
    float v = t[(size_t)row * DH + col];
    v = g1[col] * (v - st1[col]) * st1[DH + col] + be1[col];
    X[j] = make_float2(fmaxf(v, 0.f), 0.f);
  }

  // forward FFT: H = fft(h), bin = lane + 64*r
  fft_stage0<true>(X, A, lane, c0, s0);
  fft_stage_lds<1,true>(A, Bb, lane, c1, s1);
  fft_stage_lds<2,true>(Bb, A, lane, c2, s2);
  fft_stage3<true>(A, X, lane);

  // 20 diagonal segments — no LDS, no barriers
  for (int sg = 0; sg < NSEG; ++sg) {
    const float2* Gp = Gt + sg*256;
    float2 g[4];
    #pragma unroll
    for (int r = 0; r < 4; ++r) g[r] = Gp[lane + 64*r];

    float p1 = 0.f, p2 = 0.f;
    #pragma unroll
    for (int r = 0; r < 4; ++r) {
      float m  = fmaf(X[r].x, X[r].x, X[r].y * X[r].y);
      float g2 = fmaf(g[r].x, g[r].x, g[r].y * g[r].y);
      p1 += m;
      p2 = fmaf(m, g2, p2);
    }
    #pragma unroll
    for (int m = 32; m > 0; m >>= 1) {
      p1 += __shfl_xor(p1, m, 64);
      p2 += __shfl_xor(p2, m, 64);
    }
    float nh  = sqrtf(p1 * (1.f/256.f));
    float snh = fminf(fmaxf(SCRT*nh, 1e-12f), 1.f - 1e-5f);
    float lam = atanhf(snh) / snh;
    float nv  = lam * sqrtf(p2 * (1.f/256.f));
    float snv = fmaxf(SCRT*nv, 1e-12f);
    float muv = tanhf(snv) / snv;
    float sc  = alphas[sg] * muv * lam;
    float bt  = betas[sg];
    #pragma unroll
    for (int r = 0; r < 4; ++r) {
      float Ar = fmaf(sc, g[r].x, bt);
      float Bi = sc * g[r].y;
      float xr = X[r].x, xi = X[r].y;
      X[r].x = fmaf(xr, Ar, -(xi*Bi));
      X[r].y = fmaf(xr, Bi,  xi*Ar);
    }
  }

  // inverse FFT, take real part
  fft_stage0<false>(X, A, lane, c0, s0);
  fft_stage_lds<1,false>(A, Bb, lane, c1, s1);
  fft_stage_lds<2,false>(Bb, A, lane, c2, s2);
  fft_stage3<false>(A, X, lane);

  #pragma unroll
  for (int j = 0; j < 4; ++j)
    t[(size_t)row * DH + lane + 64*j] = X[j].x * (1.f/256.f);
}

// ---------- final: out = relu(bn2(h)) @ W2 + b2 ----------
__global__ __launch_bounds__(256) void final_kernel(
    const float* __restrict__ t, const float* __restrict__ st2,
    const float* __restrict__ g2, const float* __restrict__ be2,
    const float* __restrict__ W2, const float* __restrict__ b2,
    float* __restrict__ out)
{
  __shared__ __attribute__((aligned(16))) float Hs[16][260];
  __shared__ float W2s[DH*DOUT];
  __shared__ float b2s[16];
  const int tid = threadIdx.x;
  for (int idx = tid; idx < DH*DOUT; idx += 256) W2s[idx] = W2[idx];
  if (tid < DOUT) b2s[tid] = b2[tid];
  const int r0 = blockIdx.x * 16;
  for (int idx = tid; idx < 16*(DH/4); idx += 256) {
    int r  = idx >> 6;
    int c4 = (idx & 63) << 2;
    float4 v = *(const float4*)&t[(size_t)(r0 + r)*DH + c4];
    float o[4] = {v.x, v.y, v.z, v.w};
    #pragma unroll
    for (int k = 0; k < 4; ++k) {
      int c = c4 + k;
      float w = g2[c] * (o[k] - st2[c]) * st2[DH+c] + be2[c];
      o[k] = fmaxf(w, 0.f);
    }
    *(float4*)&Hs[r][c4] = make_float4(o[0], o[1], o[2], o[3]);
  }
  __syncthreads();
  if (tid < 16*DOUT) {
    int r = tid / DOUT, j = tid - DOUT*r;
    float acc = b2s[j];
    for (int k = 0; k < DH; ++k)
      acc = fmaf(Hs[r][k], W2s[k*DOUT + j], acc);
    out[(size_t)(r0 + r)*DOUT + j] = acc;
  }
}

// ---------- launch ----------
extern "C" void kernel_launch(void* const* d_in, const int* in_sizes, int n_in,
                              void* d_out, int out_size, void* d_ws, size_t ws_size,
                              hipStream_t stream) {
  const float* x      = (const float*)d_in[0];
  const float* W1     = (const float*)d_in[1];
  // d_in[2] = b1 (cancels through BN1)
  const float* g1     = (const float*)d_in[3];
  const float* be1    = (const float*)d_in[4];
  const float* Hr     = (const float*)d_in[5];
  const float* Hi     = (const float*)d_in[6];
  const float* alphas = (const float*)d_in[7];
  const float* betas  = (const float*)d_in[8];
  const float* g2     = (const float*)d_in[9];
  const float* be2    = (const float*)d_in[10];
  const float* W2     = (const float*)d_in[11];
  const float* b2     = (const float*)d_in[12];
  float* out = (float*)d_out;

  char* ws = (char*)d_ws;
  float*  t    = (float*)(ws);                 // 33,554,432 B
  char*   wsW  = ws + 33554432;                //    819,200 B
  float*  st1  = (float*)(ws + 34373632);      //      2,048 B
  float*  st2  = (float*)(ws + 34375680);      //      2,048 B
  float2* Gt   = (float2*)(ws + 34377728);     //     40,960 B

  prep_G    <<<NSEG, 256, 0, stream>>>(Hr, Hi, Gt, st1, st2);
  prep_packW<<<50, 256, 0, stream>>>(W1, wsW);
  gemm1_mfma<<<NB/64, 256, 0, stream>>>(x, wsW, t);
  colstats_kernel<<<256, 256, 0, stream>>>(t, st1, st1 + DH);
  finalize_kernel<<<1, 256, 0, stream>>>(st1);
  seg_fft   <<<NB/4, 256, 0, stream>>>(t, Gt, st1, g1, be1, alphas, betas);
  colstats_kernel<<<256, 256, 0, stream>>>(t, st2, st2 + DH);
  finalize_kernel<<<1, 256, 0, stream>>>(st2);
  final_kernel<<<NB/16, 256, 0, stream>>>(t, st2, g2, be2, W2, b2, out);
}

// Round 5
// 460.658 us; speedup vs baseline: 2.0832x; 1.2190x over previous
//
#include <hip/hip_runtime.h>
#include <math.h>

#define NB     32768
#define DH     256
#define DIN    784
#define DOUT   10
#define NSEG   20
#define EPSBN  1e-5f
#define SCRT   0.031622776601683794f   // sqrt(0.001)
#define PI_D   3.14159265358979323846

typedef _Float16 h16;
typedef _Float16 f16x8 __attribute__((ext_vector_type(8)));
typedef float    f32x4 __attribute__((ext_vector_type(4)));

// ---------- fast HW transcendentals (v_log_f32 = log2, v_exp_f32 = 2^x) ----------
__device__ __forceinline__ float flog2(float x){ float r; asm("v_log_f32 %0, %1" : "=v"(r) : "v"(x)); return r; }
__device__ __forceinline__ float fexp2(float x){ float r; asm("v_exp_f32 %0, %1" : "=v"(r) : "v"(x)); return r; }
__device__ __forceinline__ float frcp (float x){ float r; asm("v_rcp_f32 %0, %1" : "=v"(r) : "v"(x)); return r; }
__device__ __forceinline__ float fsqrt(float x){ float r; asm("v_sqrt_f32 %0, %1" : "=v"(r) : "v"(x)); return r; }

// ---------- helpers ----------
__device__ __forceinline__ void gl_lds16(const void* g, void* l){
  __builtin_amdgcn_global_load_lds(
      (const __attribute__((address_space(1))) unsigned int*)g,
      (__attribute__((address_space(3))) unsigned int*)l, 16, 0, 0);
}

__device__ __forceinline__ float2 cmul(float2 a, float2 b) {
    return make_float2(fmaf(a.x, b.x, -(a.y*b.y)), fmaf(a.x, b.y, a.y*b.x));
}
__device__ __forceinline__ float2 cadd(float2 a, float2 b){ return make_float2(a.x+b.x, a.y+b.y); }
__device__ __forceinline__ float2 csub(float2 a, float2 b){ return make_float2(a.x-b.x, a.y-b.y); }
__device__ __forceinline__ int physi(int i){ return i ^ ((i >> 4) & 15); }  // bijective LDS swizzle

// ---------- prep: Heff = H^50 (fp64) -> Gq = (gr, gi, |G|^2, 0) ; zero BN stats ----------
__global__ void prep_G(const float* __restrict__ Hr, const float* __restrict__ Hi,
                       float4* __restrict__ Gq, float* __restrict__ st1, float* __restrict__ st2)
{
  __shared__ double HrE[256], HiE[256];
  int k = threadIdx.x, s = blockIdx.x;
  double ar = (double)Hr[s*256 + k], ai = (double)Hi[s*256 + k];
  double pr = 1.0, pi = 0.0;
  for (int i = 0; i < 50; ++i){ double nr = pr*ar - pi*ai; pi = pr*ai + pi*ar; pr = nr; }
  HrE[k] = pr; HiE[k] = pi;
  if (s == 0){ st1[k] = 0.f; st1[256+k] = 0.f; st2[k] = 0.f; st2[256+k] = 0.f; }
  __syncthreads();
  int km = (256 - k) & 255;
  float gr = (float)(0.5 * (HrE[k] + HrE[km]));
  float gi = (float)(0.5 * (HiE[k] - HiE[km]));
  Gq[s*256 + k] = make_float4(gr, gi, fmaf(gr, gr, gi*gi), 0.f);
}

// ---------- pack W1 tiles: 25 k-chunks x {hi,lo}, each [256 n][32 k] fp16 swizzled ----------
__global__ void prep_packW(const float* __restrict__ W1, char* __restrict__ wsW)
{
  int blk = blockIdx.x; int ch = blk >> 1, lo = blk & 1;
  int n = threadIdx.x;
  char* out = wsW + (size_t)ch*32768 + lo*16384;
  int xr = (n & 3) << 4;
  #pragma unroll
  for (int j = 0; j < 32; ++j){
    int w  = 2*j;
    int k2 = (w ^ xr) >> 1;
    int k  = ch*32 + k2;
    float v = (k < 784) ? W1[(size_t)k*256 + n] : 0.f;
    h16 hv = (h16)v;
    h16 ov = lo ? (h16)(v - (float)hv) : hv;
    *(h16*)(out + n*64 + w) = ov;
  }
}

// ---------- GEMM1: t = x @ W1, 128x256 tile, fp16 3-term split (b1 cancels through BN1) ----------
__global__ __launch_bounds__(512) void gemm1_mfma(const float* __restrict__ x,
                                                  const char* __restrict__ wsW,
                                                  float* __restrict__ t)
{
  __shared__ __attribute__((aligned(16))) char AB[2][16384]; // hi 8K, lo 8K  [128r][64B]
  __shared__ __attribute__((aligned(16))) char BB[2][32768]; // hi 16K, lo 16K [256n][64B]
  const int tid = threadIdx.x;
  const int lane = tid & 63, wid = tid >> 6;
  const int cl = lane & 15, g4 = lane >> 4;
  const int wr = wid >> 1, wc = wid & 1;
  const int brow = blockIdx.x * 128;
  const int arow = tid >> 2, asl = tid & 3;          // A-staging: row, 16B slot
  const int aoff = arow*64 + ((asl*16) ^ ((arow & 3) << 4));
  const float* xrow = x + (size_t)(brow + arow)*784;

  f32x4 acc[2][8];
  #pragma unroll
  for (int i = 0; i < 2; ++i)
    #pragma unroll
    for (int j = 0; j < 8; ++j) acc[i][j] = (f32x4){0.f,0.f,0.f,0.f};

  const float4 z4 = make_float4(0.f,0.f,0.f,0.f);

  // prologue: stage chunk 0 (B via gl_lds; A via load+cvt+ds_write)
  #pragma unroll
  for (int q = 0; q < 4; ++q)
    gl_lds16(wsW + q*8192 + wid*1024 + lane*16, &BB[0][0] + q*8192 + wid*1024);
  {
    const float* p = xrow + asl*8;
    float4 a0 = *(const float4*)p, a1 = *(const float4*)(p + 4);
    float vv[8] = {a0.x,a0.y,a0.z,a0.w,a1.x,a1.y,a1.z,a1.w};
    f16x8 hv, lv;
    #pragma unroll
    for (int j = 0; j < 8; ++j){ h16 hh = (h16)vv[j]; hv[j] = hh; lv[j] = (h16)(vv[j] - (float)hh); }
    *(f16x8*)(&AB[0][0] + aoff) = hv;
    *(f16x8*)(&AB[0][0] + 8192 + aoff) = lv;
  }
  __syncthreads();

  int cur = 0;
  for (int ch = 0; ch < 25; ++ch){
    const bool hn = (ch < 24);
    float4 na0 = z4, na1 = z4;
    if (hn){
      // issue next B stage (async) + next A loads (regs)
      const char* src = wsW + (size_t)(ch+1)*32768;
      #pragma unroll
      for (int q = 0; q < 4; ++q)
        gl_lds16(src + q*8192 + wid*1024 + lane*16, &BB[cur^1][0] + q*8192 + wid*1024);
      int kg = (ch+1)*32 + asl*8;
      if (kg < 784){
        const float* p = xrow + kg;
        na0 = *(const float4*)p; na1 = *(const float4*)(p + 4);
      }
    }
    // compute chunk ch
    const char* Ac = &AB[cur][0];
    const char* Bc = &BB[cur][0];
    f16x8 ah[2], al[2];
    #pragma unroll
    for (int mi = 0; mi < 2; ++mi){
      int row = wr*32 + mi*16 + cl;
      int off = row*64 + ((g4*16) ^ ((row & 3) << 4));
      ah[mi] = *(const f16x8*)(Ac + off);
      al[mi] = *(const f16x8*)(Ac + 8192 + off);
    }
    #pragma unroll
    for (int ni = 0; ni < 8; ++ni){
      int n = wc*128 + ni*16 + cl;
      int boff = n*64 + ((g4*16) ^ ((n & 3) << 4));
      f16x8 bh = *(const f16x8*)(Bc + boff);
      f16x8 bl = *(const f16x8*)(Bc + 16384 + boff);
      #pragma unroll
      for (int mi = 0; mi < 2; ++mi){
        acc[mi][ni] = __builtin_amdgcn_mfma_f32_16x16x32_f16(ah[mi], bh, acc[mi][ni], 0,0,0);
        acc[mi][ni] = __builtin_amdgcn_mfma_f32_16x16x32_f16(al[mi], bh, acc[mi][ni], 0,0,0);
        acc[mi][ni] = __builtin_amdgcn_mfma_f32_16x16x32_f16(ah[mi], bl, acc[mi][ni], 0,0,0);
      }
    }
    if (hn){
      float vv[8] = {na0.x,na0.y,na0.z,na0.w,na1.x,na1.y,na1.z,na1.w};
      f16x8 hv, lv;
      #pragma unroll
      for (int j = 0; j < 8; ++j){ h16 hh = (h16)vv[j]; hv[j] = hh; lv[j] = (h16)(vv[j] - (float)hh); }
      *(f16x8*)(&AB[cur^1][0] + aoff) = hv;
      *(f16x8*)(&AB[cur^1][0] + 8192 + aoff) = lv;
      __syncthreads();
      cur ^= 1;
    }
  }
  // store
  #pragma unroll
  for (int mi = 0; mi < 2; ++mi)
    #pragma unroll
    for (int ni = 0; ni < 8; ++ni)
      #pragma unroll
      for (int r = 0; r < 4; ++r){
        int row = brow + wr*32 + mi*16 + g4*4 + r;
        int col = wc*128 + ni*16 + cl;
        t[(size_t)row*256 + col] = acc[mi][ni][r];
      }
}

// ---------- column stats ----------
__global__ __launch_bounds__(256) void colstats_kernel(const float* __restrict__ t,
                                                       float* __restrict__ sum,
                                                       float* __restrict__ ssq)
{
  const int col = threadIdx.x;
  float s = 0.f, q = 0.f;
  for (int r = blockIdx.x; r < NB; r += gridDim.x){
    float v = t[(size_t)r * DH + col];
    s += v; q = fmaf(v, v, q);
  }
  atomicAdd(&sum[col], s);
  atomicAdd(&ssq[col], q);
}

__global__ void finalize_kernel(float* __restrict__ st)
{
  int j = threadIdx.x;
  float mu = st[j] * (1.f/(float)NB);
  float var = st[DH+j] * (1.f/(float)NB) - mu*mu;
  st[j] = mu;
  st[DH+j] = rsqrtf(var + EPSBN);
}

// ---------- FFT pieces (radix-4 Stockham, N=256, 1 wave per row; validated R0-R4) ----------
template<bool FWD>
__device__ __forceinline__ void fft_stage0(const float2 X[4], float2* dst, int lane, float wc, float ws)
{
    float2 a=X[0], b=X[1], c=X[2], d=X[3];
    float2 t0 = cadd(a,c), t1 = csub(a,c), t2 = cadd(b,d), bd = csub(b,d);
    float2 t3 = FWD ? make_float2(bd.y, -bd.x) : make_float2(-bd.y, bd.x);
    float2 w1 = make_float2(wc, FWD ? -ws : ws);
    float2 w2 = cmul(w1,w1);
    float2 w3 = cmul(w2,w1);
    int j = lane << 2;
    dst[physi(j)]   = cadd(t0,t2);
    dst[physi(j+1)] = cmul(cadd(t1,t3), w1);
    dst[physi(j+2)] = cmul(csub(t0,t2), w2);
    dst[physi(j+3)] = cmul(csub(t1,t3), w3);
}

template<int TT, bool FWD>
__device__ __forceinline__ void fft_stage_lds(const float2* src, float2* dst, int lane, float wc, float ws)
{
    const int s_ = 1 << (2*TT);
    int i = lane;
    float2 a = src[physi(i)];
    float2 b = src[physi(i+64)];
    float2 c = src[physi(i+128)];
    float2 d = src[physi(i+192)];
    float2 t0 = cadd(a,c), t1 = csub(a,c), t2 = cadd(b,d), bd = csub(b,d);
    float2 t3 = FWD ? make_float2(bd.y, -bd.x) : make_float2(-bd.y, bd.x);
    float2 w1 = make_float2(wc, FWD ? -ws : ws);
    float2 w2 = cmul(w1,w1);
    float2 w3 = cmul(w2,w1);
    int j = i + 3*(i & ~(s_-1));
    dst[physi(j)]      = cadd(t0,t2);
    dst[physi(j+s_)]   = cmul(cadd(t1,t3), w1);
    dst[physi(j+2*s_)] = cmul(csub(t0,t2), w2);
    dst[physi(j+3*s_)] = cmul(csub(t1,t3), w3);
}

template<bool FWD>
__device__ __forceinline__ void fft_stage3(const float2* src, float2 X[4], int lane)
{
    float2 a = src[physi(lane)];
    float2 b = src[physi(lane+64)];
    float2 c = src[physi(lane+128)];
    float2 d = src[physi(lane+192)];
    float2 t0 = cadd(a,c), t1 = csub(a,c), t2 = cadd(b,d), bd = csub(b,d);
    float2 t3 = FWD ? make_float2(bd.y, -bd.x) : make_float2(-bd.y, bd.x);
    X[0] = cadd(t0,t2);
    X[1] = cadd(t1,t3);
    X[2] = csub(t0,t2);
    X[3] = csub(t1,t3);
}

// ---------- segments: one fft, 20x diagonal update H *= (sc*G + bt), one ifft ----------
__global__ __launch_bounds__(256) void seg_fft(
    float* __restrict__ t, const float4* __restrict__ Gq,
    const float* __restrict__ st1,
    const float* __restrict__ g1, const float* __restrict__ be1,
    const float* __restrict__ alphas, const float* __restrict__ betas)
{
  __shared__ float2 bufA[4][256];
  __shared__ float2 bufB[4][256];
  const int lane = threadIdx.x & 63;
  const int wid  = threadIdx.x >> 6;
  const int row  = (blockIdx.x << 2) | wid;
  float2* A  = bufA[wid];
  float2* Bb = bufB[wid];

  float c0,s0,c1,s1,c2,s2;
  {
    const float k = 6.283185307179586f / 256.f;
    sincosf(k * (float)lane,          &s0, &c0);
    sincosf(k * (float)(lane & ~3),   &s1, &c1);
    sincosf(k * (float)(lane & ~15),  &s2, &c2);
  }

  // load + BN1 + relu
  float2 X[4];
  #pragma unroll
  for (int j = 0; j < 4; ++j) {
    int col = lane + 64*j;
    float v = t[(size_t)row * DH + col];
    v = g1[col] * (v - st1[col]) * st1[DH + col] + be1[col];
    X[j] = make_float2(fmaxf(v, 0.f), 0.f);
  }

  // forward FFT
  fft_stage0<true>(X, A, lane, c0, s0);
  fft_stage_lds<1,true>(A, Bb, lane, c1, s1);
  fft_stage_lds<2,true>(Bb, A, lane, c2, s2);
  fft_stage3<true>(A, X, lane);

  // 20 diagonal segments — no LDS, no barriers
  const int upper = lane & 32;
  for (int sg = 0; sg < NSEG; ++sg) {
    const float4* Gp = Gq + sg*256;
    float4 g[4];
    #pragma unroll
    for (int r = 0; r < 4; ++r) g[r] = Gp[lane + 64*r];

    float p1 = 0.f, p2 = 0.f;
    #pragma unroll
    for (int r = 0; r < 4; ++r) {
      float m = fmaf(X[r].x, X[r].x, X[r].y * X[r].y);
      p1 += m;
      p2 = fmaf(m, g[r].z, p2);
    }
    // dual reduce: 7 shuffles for both sums
    float send = upper ? p1 : p2;
    float recv = __shfl_xor(send, 32, 64);
    float w = (upper ? p2 : p1) + recv;
    #pragma unroll
    for (int m = 1; m <= 16; m <<= 1) w += __shfl_xor(w, m, 64);
    float wsw = __shfl_xor(w, 32, 64);
    float P1 = upper ? wsw : w;
    float P2 = upper ? w   : wsw;

    // scalars via HW transcendentals
    float nh  = fsqrt(P1 * (1.f/256.f));
    float sn  = fminf(fmaxf(SCRT*nh, 1e-12f), 1.f - 1e-5f);
    float lam = 0.34657359028f * flog2((1.f+sn) * frcp(1.f-sn)) * frcp(sn);  // atanh(sn)/sn
    float nv  = lam * fsqrt(P2 * (1.f/256.f));
    float snv = fmaxf(SCRT*nv, 1e-12f);
    float e   = fexp2(fminf(snv, 40.f) * 2.88539008178f);                    // exp(2*snv)
    float muv = (e - 1.f) * frcp((e + 1.f) * snv);                           // tanh(snv)/snv
    float sc  = alphas[sg] * muv * lam;
    float bt  = betas[sg];

    #pragma unroll
    for (int r = 0; r < 4; ++r) {
      float Ar = fmaf(sc, g[r].x, bt);
      float Bi = sc * g[r].y;
      float xr = X[r].x, xi = X[r].y;
      X[r].x = fmaf(xr, Ar, -(xi*Bi));
      X[r].y = fmaf(xr, Bi,  xi*Ar);
    }
  }

  // inverse FFT, real part
  fft_stage0<false>(X, A, lane, c0, s0);
  fft_stage_lds<1,false>(A, Bb, lane, c1, s1);
  fft_stage_lds<2,false>(Bb, A, lane, c2, s2);
  fft_stage3<false>(A, X, lane);

  #pragma unroll
  for (int j = 0; j < 4; ++j)
    t[(size_t)row * DH + lane + 64*j] = X[j].x * (1.f/256.f);
}

// ---------- final: out = relu(bn2(h)) @ W2 + b2 ----------
__global__ __launch_bounds__(256) void final_kernel(
    const float* __restrict__ t, const float* __restrict__ st2,
    const float* __restrict__ g2, const float* __restrict__ be2,
    const float* __restrict__ W2, const float* __restrict__ b2,
    float* __restrict__ out)
{
  __shared__ __attribute__((aligned(16))) float Hs[16][260];
  __shared__ float W2s[DH*DOUT];
  __shared__ float b2s[16];
  const int tid = threadIdx.x;
  for (int idx = tid; idx < DH*DOUT; idx += 256) W2s[idx] = W2[idx];
  if (tid < DOUT) b2s[tid] = b2[tid];
  const int r0 = blockIdx.x * 16;
  for (int idx = tid; idx < 16*(DH/4); idx += 256) {
    int r  = idx >> 6;
    int c4 = (idx & 63) << 2;
    float4 v = *(const float4*)&t[(size_t)(r0 + r)*DH + c4];
    float o[4] = {v.x, v.y, v.z, v.w};
    #pragma unroll
    for (int k = 0; k < 4; ++k) {
      int c = c4 + k;
      float w = g2[c] * (o[k] - st2[c]) * st2[DH+c] + be2[c];
      o[k] = fmaxf(w, 0.f);
    }
    *(float4*)&Hs[r][c4] = make_float4(o[0], o[1], o[2], o[3]);
  }
  __syncthreads();
  if (tid < 16*DOUT) {
    int r = tid / DOUT, j = tid - DOUT*r;
    float acc = b2s[j];
    for (int k = 0; k < DH; ++k)
      acc = fmaf(Hs[r][k], W2s[k*DOUT + j], acc);
    out[(size_t)(r0 + r)*DOUT + j] = acc;
  }
}

// ---------- launch ----------
extern "C" void kernel_launch(void* const* d_in, const int* in_sizes, int n_in,
                              void* d_out, int out_size, void* d_ws, size_t ws_size,
                              hipStream_t stream) {
  const float* x      = (const float*)d_in[0];
  const float* W1     = (const float*)d_in[1];
  // d_in[2] = b1 (cancels through BN1)
  const float* g1     = (const float*)d_in[3];
  const float* be1    = (const float*)d_in[4];
  const float* Hr     = (const float*)d_in[5];
  const float* Hi     = (const float*)d_in[6];
  const float* alphas = (const float*)d_in[7];
  const float* betas  = (const float*)d_in[8];
  const float* g2     = (const float*)d_in[9];
  const float* be2    = (const float*)d_in[10];
  const float* W2     = (const float*)d_in[11];
  const float* b2     = (const float*)d_in[12];
  float* out = (float*)d_out;

  char* ws = (char*)d_ws;
  float*  t    = (float*)(ws);                 // 33,554,432 B
  char*   wsW  = ws + 33554432;                //    819,200 B
  float*  st1  = (float*)(ws + 34373632);      //      2,048 B
  float*  st2  = (float*)(ws + 34375680);      //      2,048 B
  float4* Gq   = (float4*)(ws + 34377728);     //     81,920 B

  prep_G    <<<NSEG, 256, 0, stream>>>(Hr, Hi, Gq, st1, st2);
  prep_packW<<<50, 256, 0, stream>>>(W1, wsW);
  gemm1_mfma<<<NB/128, 512, 0, stream>>>(x, wsW, t);
  colstats_kernel<<<2048, 256, 0, stream>>>(t, st1, st1 + DH);
  finalize_kernel<<<1, 256, 0, stream>>>(st1);
  seg_fft   <<<NB/4, 256, 0, stream>>>(t, Gq, st1, g1, be1, alphas, betas);
  colstats_kernel<<<2048, 256, 0, stream>>>(t, st2, st2 + DH);
  finalize_kernel<<<1, 256, 0, stream>>>(st2);
  final_kernel<<<NB/16, 256, 0, stream>>>(t, st2, g2, be2, W2, b2, out);
}